// Round 2
// baseline (309.829 us; speedup 1.0000x reference)
//
#include <hip/hip_runtime.h>
#include <hip/hip_bf16.h>
#include <stdint.h>

// SparseSwiGLU on MI355X: counting-sort densify COO -> bf16 weights, then MFMA GEMMs.
// T=512 tokens, DIM=1024, HIDDEN=4096, NNZ=262144 per matrix.
//
// Workspace layout (<= 29 MB):
//   [0,    8MB)  WUP    bf16 [4096][1024]   (B^T for up GEMM, K-contiguous)
//   [8MB, 16MB)  WGATE  bf16 [4096][1024]
//   [16MB,24MB)  WDOWN  bf16 [1024][4096]
//   [24MB,25MB)  XB     bf16 [512][1024]
//   [25MB,29MB)  HID    bf16 [512][4096]    -- ALIASED by PACKED (3MB) until
//                                              gemm_upgate runs (packed dead by then)
//   [28MB,...)   cnt[9216] / start[9217] / cur[9216] ints (120 KB)

#define DIM_    1024
#define HIDDEN_ 4096
#define NNZ_    262144
#define TTOK_   512
#define NBUCK_  9216            // 4096 up + 4096 gate + 1024 down rows

typedef __attribute__((ext_vector_type(8))) short short8;
typedef __attribute__((ext_vector_type(4))) float float4v;

__device__ inline unsigned short f2bf(float f) {
    union { float f; unsigned int u; } c; c.f = f;
    unsigned int u = c.u;
    unsigned int r = u + 0x7fffu + ((u >> 16) & 1u);   // RNE
    return (unsigned short)(r >> 16);
}
__device__ inline float bf2f(unsigned short h) {
    union { unsigned int u; float f; } c; c.u = ((unsigned int)h) << 16;
    return c.f;
}

__device__ inline void async16(const unsigned short* g, unsigned short* l) {
    __builtin_amdgcn_global_load_lds(
        (const __attribute__((address_space(1))) unsigned int*)g,
        (__attribute__((address_space(3))) unsigned int*)l, 16, 0, 0);
}

// -------------------------------------------------- k1: count + x-prep
// [0,3*NNZ): histogram rows into cnt[] (L2-resident atomics);
// [3NNZ, 3NNZ+XC): x -> bf16; [3NNZ+XC, 3NNZ+2XC): out = x + down_bias.
#define XC_ ((TTOK_ * DIM_) / 4)           // 131072

__global__ void count_prep_kernel(const int* __restrict__ ur,
                                  const int* __restrict__ gr,
                                  const int* __restrict__ dr,
                                  const float* __restrict__ x,
                                  const float* __restrict__ down_bias,
                                  int* __restrict__ cnt,
                                  unsigned short* __restrict__ xb,
                                  float* __restrict__ out) {
    unsigned int id = blockIdx.x * blockDim.x + threadIdx.x;
    if (id < NNZ_) {
        atomicAdd(&cnt[ur[id]], 1);
    } else if (id < 2u * NNZ_) {
        atomicAdd(&cnt[4096 + gr[id - NNZ_]], 1);
    } else if (id < 3u * NNZ_) {
        atomicAdd(&cnt[8192 + dr[id - 2u * NNZ_]], 1);
    } else if (id < 3u * NNZ_ + XC_) {
        int i = id - 3u * NNZ_;
        float4 v = ((const float4*)x)[i];
        ushort4 o;
        o.x = f2bf(v.x); o.y = f2bf(v.y); o.z = f2bf(v.z); o.w = f2bf(v.w);
        ((ushort4*)xb)[i] = o;
    } else {
        int i = id - 3u * NNZ_ - XC_;
        float4 v = ((const float4*)x)[i];
        int d = (i * 4) & (DIM_ - 1);
        const float4 b = *(const float4*)(down_bias + d);
        float4 o;
        o.x = v.x + b.x; o.y = v.y + b.y; o.z = v.z + b.z; o.w = v.w + b.w;
        ((float4*)out)[i] = o;
    }
}

// -------------------------------------------------- k2: exclusive scan (1 block)
// 9216 = 256 threads x 36 elements. Global offsets: up rows own [0,NNZ),
// gate [NNZ,2NNZ), down [2NNZ,3NNZ) automatically (totals are exact).
__global__ __launch_bounds__(256) void scan_kernel(const int* __restrict__ cnt,
                                                   int* __restrict__ start,
                                                   int* __restrict__ cur) {
    __shared__ int part[256];
    const int t = threadIdx.x;
    const int base = t * 36;
    int vals[36];
    int s = 0;
    for (int i = 0; i < 36; ++i) { vals[i] = cnt[base + i]; s += vals[i]; }
    part[t] = s;
    __syncthreads();
    for (int off = 1; off < 256; off <<= 1) {
        int v = part[t];
        int add = (t >= off) ? part[t - off] : 0;
        __syncthreads();
        part[t] = v + add;
        __syncthreads();
    }
    int ex = (t == 0) ? 0 : part[t - 1];
    for (int i = 0; i < 36; ++i) {
        start[base + i] = ex;
        cur[base + i] = ex;
        ex += vals[i];
    }
    if (t == 255) start[NBUCK_] = ex;   // == 3*NNZ sentinel
}

// -------------------------------------------------- k3: bucket into row-sorted order
// packed entry = (col << 16) | bf16(val). Writes land in a 3 MB L2-resident array.
__global__ void bucket_kernel(const int* __restrict__ ur, const int* __restrict__ uc,
                              const float* __restrict__ uv,
                              const int* __restrict__ gr, const int* __restrict__ gc,
                              const float* __restrict__ gv,
                              const int* __restrict__ dr, const int* __restrict__ dc,
                              const float* __restrict__ dv,
                              int* __restrict__ cur,
                              unsigned int* __restrict__ packed) {
    unsigned int id = blockIdx.x * blockDim.x + threadIdx.x;
    int bucket, col; float val;
    if (id < NNZ_) {
        bucket = ur[id];            col = uc[id]; val = uv[id];
    } else if (id < 2u * NNZ_) {
        unsigned int j = id - NNZ_;
        bucket = 4096 + gr[j];      col = gc[j];  val = gv[j];
    } else {
        unsigned int j = id - 2u * NNZ_;
        bucket = 8192 + dr[j];      col = dc[j];  val = dv[j];
    }
    int pos = atomicAdd(&cur[bucket], 1);
    packed[pos] = ((unsigned int)col << 16) | (unsigned int)f2bf(val);
}

// -------------------------------------------------- k4: build one weight row per block
// LDS fp32 row buffer absorbs duplicates via ds atomics; streams bf16 row out.
__global__ __launch_bounds__(256) void build_kernel(const unsigned int* __restrict__ packed,
                                                    const int* __restrict__ start,
                                                    unsigned short* __restrict__ WUP,
                                                    unsigned short* __restrict__ WGATE,
                                                    unsigned short* __restrict__ WDOWN) {
    __shared__ float buf[4096];
    const int b = blockIdx.x;
    const int t = threadIdx.x;
    int width;
    unsigned short* Wrow;
    if (b < 4096)      { width = 1024; Wrow = WUP + b * 1024; }
    else if (b < 8192) { width = 1024; Wrow = WGATE + (b - 4096) * 1024; }
    else               { width = 4096; Wrow = WDOWN + (b - 8192) * 4096; }

    for (int c = t * 4; c < width; c += 1024)
        *(float4*)&buf[c] = make_float4(0.f, 0.f, 0.f, 0.f);
    __syncthreads();

    const int s0 = start[b], s1 = start[b + 1];
    for (int i = s0 + t; i < s1; i += 256) {
        unsigned int e = packed[i];
        atomicAdd(&buf[e >> 16], bf2f((unsigned short)(e & 0xffffu)));
    }
    __syncthreads();

    for (int c = t * 4; c < width; c += 1024) {
        ushort4 o;
        o.x = f2bf(buf[c]);     o.y = f2bf(buf[c + 1]);
        o.z = f2bf(buf[c + 2]); o.w = f2bf(buf[c + 3]);
        *(ushort4*)(Wrow + c) = o;
    }
}

// -------------------------------------------------- up+gate GEMM (unchanged R1)
__global__ __launch_bounds__(256) void gemm_upgate_kernel(
    const unsigned short* __restrict__ xb,      // [512][1024]
    const unsigned short* __restrict__ wup,     // [4096][1024]
    const unsigned short* __restrict__ wgate,   // [4096][1024]
    const float* __restrict__ up_bias,
    const float* __restrict__ gate_bias,
    unsigned short* __restrict__ hid) {         // [512][4096]
    __shared__ unsigned short sA[64 * 32];
    __shared__ unsigned short sB[128 * 32];
    const int t = threadIdx.x;
    const int m0 = blockIdx.y * 64;
    const int n0 = blockIdx.x * 128;
    const int w = t >> 6, l = t & 63;
    const int wm = (w >> 1) * 32, wn = (w & 1) * 64;
    const int lr = l & 15, lkq = (l >> 4);

    float4v acc[2][2][4];
    for (int p = 0; p < 2; ++p)
        for (int im = 0; im < 2; ++im)
            for (int in = 0; in < 4; ++in)
                acc[p][im][in] = float4v{0.f, 0.f, 0.f, 0.f};

    const int srow = t >> 2, scol = (t & 3) * 8;

    for (int p = 0; p < 2; ++p) {
        const unsigned short* W = p ? wgate : wup;
        for (int k0 = 0; k0 < DIM_; k0 += 32) {
            async16(xb + (m0 + srow) * DIM_ + k0 + scol, &sA[t * 8]);
            async16(W + (n0 + srow) * DIM_ + k0 + scol, &sB[t * 8]);
            async16(W + (n0 + 64 + srow) * DIM_ + k0 + scol, &sB[(t + 256) * 8]);
            __syncthreads();
            short8 a[2], b[4];
            for (int im = 0; im < 2; ++im)
                a[im] = *(const short8*)&sA[(wm + im * 16 + lr) * 32 + lkq * 8];
            for (int in = 0; in < 4; ++in)
                b[in] = *(const short8*)&sB[(wn + in * 16 + lr) * 32 + lkq * 8];
            for (int im = 0; im < 2; ++im)
                for (int in = 0; in < 4; ++in)
                    acc[p][im][in] = __builtin_amdgcn_mfma_f32_16x16x32_bf16(
                        a[im], b[in], acc[p][im][in], 0, 0, 0);
            __syncthreads();
        }
    }

    for (int im = 0; im < 2; ++im) {
        for (int in = 0; in < 4; ++in) {
            const int n = n0 + wn + in * 16 + lr;
            const float ub = up_bias[n], gb = gate_bias[n];
            for (int r = 0; r < 4; ++r) {
                const int m = m0 + wm + im * 16 + lkq * 4 + r;
                const float u = acc[0][im][in][r] + ub;
                const float g = acc[1][im][in][r] + gb;
                const float h = (u / (1.f + __expf(-u))) * g;
                hid[m * HIDDEN_ + n] = f2bf(h);
            }
        }
    }
}

// -------------------------------------------------- down GEMM (unchanged R1)
__global__ __launch_bounds__(256) void gemm_down_kernel(
    const unsigned short* __restrict__ hid,     // [512][4096]
    const unsigned short* __restrict__ wdown,   // [1024][4096]
    float* __restrict__ out) {                  // [512][1024]
    __shared__ unsigned short sA[64 * 32];
    __shared__ unsigned short sB[64 * 32];
    const int t = threadIdx.x;
    const int n0 = blockIdx.x * 64;
    const int m0 = blockIdx.y * 64;
    const int kb = blockIdx.z * 1024;
    const int w = t >> 6, l = t & 63;
    const int wm = (w >> 1) * 32, wn = (w & 1) * 32;
    const int lr = l & 15, lkq = (l >> 4);

    float4v acc[2][2];
    for (int im = 0; im < 2; ++im)
        for (int in = 0; in < 2; ++in)
            acc[im][in] = float4v{0.f, 0.f, 0.f, 0.f};

    const int srow = t >> 2, scol = (t & 3) * 8;

    for (int k0 = kb; k0 < kb + 1024; k0 += 32) {
        async16(hid + (m0 + srow) * HIDDEN_ + k0 + scol, &sA[t * 8]);
        async16(wdown + (n0 + srow) * HIDDEN_ + k0 + scol, &sB[t * 8]);
        __syncthreads();
        short8 a[2], b[2];
        for (int im = 0; im < 2; ++im)
            a[im] = *(const short8*)&sA[(wm + im * 16 + lr) * 32 + lkq * 8];
        for (int in = 0; in < 2; ++in)
            b[in] = *(const short8*)&sB[(wn + in * 16 + lr) * 32 + lkq * 8];
        for (int im = 0; im < 2; ++im)
            for (int in = 0; in < 2; ++in)
                acc[im][in] = __builtin_amdgcn_mfma_f32_16x16x32_bf16(
                    a[im], b[in], acc[im][in], 0, 0, 0);
        __syncthreads();
    }

    for (int im = 0; im < 2; ++im) {
        for (int in = 0; in < 2; ++in) {
            const int n = n0 + wn + in * 16 + lr;
            for (int r = 0; r < 4; ++r) {
                const int m = m0 + wm + im * 16 + lkq * 4 + r;
                atomicAdd(out + m * DIM_ + n, acc[im][in][r]);
            }
        }
    }
}

// -------------------------------------------------- launch
extern "C" void kernel_launch(void* const* d_in, const int* in_sizes, int n_in,
                              void* d_out, int out_size, void* d_ws, size_t ws_size,
                              hipStream_t stream) {
    const float* x         = (const float*)d_in[0];
    const int*   up_row    = (const int*)d_in[1];
    const int*   up_col    = (const int*)d_in[2];
    const float* up_val    = (const float*)d_in[3];
    const float* up_bias   = (const float*)d_in[4];
    const int*   gate_row  = (const int*)d_in[5];
    const int*   gate_col  = (const int*)d_in[6];
    const float* gate_val  = (const float*)d_in[7];
    const float* gate_bias = (const float*)d_in[8];
    const int*   down_row  = (const int*)d_in[9];
    const int*   down_col  = (const int*)d_in[10];
    const float* down_val  = (const float*)d_in[11];
    const float* down_bias = (const float*)d_in[12];
    float* out = (float*)d_out;

    unsigned char* ws = (unsigned char*)d_ws;
    unsigned short* WUP    = (unsigned short*)(ws);
    unsigned short* WGATE  = (unsigned short*)(ws + (8u << 20));
    unsigned short* WDOWN  = (unsigned short*)(ws + (16u << 20));
    unsigned short* XB     = (unsigned short*)(ws + (24u << 20));
    unsigned short* HID    = (unsigned short*)(ws + (25u << 20));
    unsigned int*   PACKED = (unsigned int*)(ws + (25u << 20));   // aliases HID; dead before HID written
    int*            CNT    = (int*)(ws + (28u << 20));
    int*            START  = (int*)(ws + (28u << 20) + 40960);
    int*            CUR    = (int*)(ws + (28u << 20) + 81920);

    hipMemsetAsync(CNT, 0, NBUCK_ * sizeof(int), stream);

    // 3*NNZ + 2*XC = 1,048,576 threads exactly
    count_prep_kernel<<<4096, 256, 0, stream>>>(
        up_row, gate_row, down_row, x, down_bias, CNT, XB, out);

    scan_kernel<<<1, 256, 0, stream>>>(CNT, START, CUR);

    bucket_kernel<<<3 * NNZ_ / 256, 256, 0, stream>>>(
        up_row, up_col, up_val, gate_row, gate_col, gate_val,
        down_row, down_col, down_val, CUR, PACKED);

    build_kernel<<<NBUCK_, 256, 0, stream>>>(PACKED, START, WUP, WGATE, WDOWN);

    gemm_upgate_kernel<<<dim3(HIDDEN_ / 128, TTOK_ / 64), 256, 0, stream>>>(
        XB, WUP, WGATE, up_bias, gate_bias, HID);

    gemm_down_kernel<<<dim3(DIM_ / 64, TTOK_ / 64, 4), 256, 0, stream>>>(
        HID, WDOWN, out);
}

// Round 3
// 176.416 us; speedup vs baseline: 1.7562x; 1.7562x over previous
//
#include <hip/hip_runtime.h>
#include <hip/hip_bf16.h>
#include <stdint.h>

// SparseSwiGLU on MI355X: densify COO -> bf16 dense weights (HW pk_add_bf16
// atomics), then MFMA GEMMs.
// T=512 tokens, DIM=1024, HIDDEN=4096, NNZ=262144 per matrix.
//
// Workspace layout (<= 29 MB):
//   [0,    8MB)  WUP   bf16 [4096][1024]   (B^T for up GEMM, K-contiguous)
//   [8MB, 16MB)  WGATE bf16 [4096][1024]
//   [16MB,24MB)  WDOWN bf16 [1024][4096]
//   [24MB,25MB)  XB    bf16 [512][1024]
//   [25MB,29MB)  HID   bf16 [512][4096]

#define DIM_    1024
#define HIDDEN_ 4096
#define NNZ_    262144
#define TTOK_   512

typedef __attribute__((ext_vector_type(8))) short short8;
typedef __attribute__((ext_vector_type(4))) float float4v;
typedef __attribute__((ext_vector_type(2))) short short2v;

__device__ inline unsigned short f2bf(float f) {
    union { float f; unsigned int u; } c; c.f = f;
    unsigned int u = c.u;
    unsigned int r = u + 0x7fffu + ((u >> 16) & 1u);   // RNE
    return (unsigned short)(r >> 16);
}
__device__ inline float bf2f(unsigned short h) {
    union { unsigned int u; float f; } c; c.u = ((unsigned int)h) << 16;
    return c.f;
}

__device__ inline void async16(const unsigned short* g, unsigned short* l) {
    __builtin_amdgcn_global_load_lds(
        (const __attribute__((address_space(1))) unsigned int*)g,
        (__attribute__((address_space(3))) unsigned int*)l, 16, 0, 0);
}

// ---------------------------------------------------------------- prep
// [0,ZN): zero 16B chunks of the 24MB weight region;
// [ZN,ZN+XC): x -> bf16 (4/thread); [ZN+XC,ZN+2XC): out = x + down_bias.
#define ZN_ ((24u << 20) / 16u)            // 1572864
#define XC_ ((TTOK_ * DIM_) / 4)           // 131072

__global__ void prep_kernel(const float* __restrict__ x,
                            const float* __restrict__ down_bias,
                            uint4* __restrict__ wzero,
                            unsigned short* __restrict__ xb,
                            float* __restrict__ out) {
    unsigned int id = blockIdx.x * blockDim.x + threadIdx.x;
    if (id < ZN_) {
        wzero[id] = make_uint4(0u, 0u, 0u, 0u);
    } else if (id < ZN_ + XC_) {
        int i = id - ZN_;
        float4 v = ((const float4*)x)[i];
        ushort4 o;
        o.x = f2bf(v.x); o.y = f2bf(v.y); o.z = f2bf(v.z); o.w = f2bf(v.w);
        ((ushort4*)xb)[i] = o;
    } else if (id < ZN_ + 2 * XC_) {
        int i = id - ZN_ - XC_;
        float4 v = ((const float4*)x)[i];
        int d = (i * 4) & (DIM_ - 1);
        const float4 b = *(const float4*)(down_bias + d);
        float4 o;
        o.x = v.x + b.x; o.y = v.y + b.y; o.z = v.z + b.z; o.w = v.w + b.w;
        ((float4*)out)[i] = o;
    }
}

// ---------------------------------------------------------------- scatter
// Fire-and-forget HW packed-bf16 atomic add: no return, no CAS retry chain.
// Adding bf16 +0 to the partner half is exact (x + 0 == x).
__device__ inline void add_bf16(unsigned short* W, int idx, float v) {
#if __has_builtin(__builtin_amdgcn_global_atomic_fadd_v2bf16)
    unsigned short* base = W + (idx & ~1);
    const unsigned short hv = f2bf(v);
    short2v pk;
    if (idx & 1) { pk[0] = 0; pk[1] = (short)hv; }
    else         { pk[0] = (short)hv; pk[1] = 0; }
    __builtin_amdgcn_global_atomic_fadd_v2bf16(
        (__attribute__((address_space(1))) short2v*)base, pk);
#else
    unsigned int* p = (unsigned int*)(W + (idx & ~1));
    const bool hi = idx & 1;
    unsigned int old = *p, assumed;
    do {
        assumed = old;
        unsigned short h = hi ? (unsigned short)(assumed >> 16)
                              : (unsigned short)(assumed & 0xffffu);
        unsigned short nh = f2bf(bf2f(h) + v);
        unsigned int nw = hi ? ((assumed & 0x0000ffffu) | ((unsigned int)nh << 16))
                             : ((assumed & 0xffff0000u) | (unsigned int)nh);
        old = atomicCAS(p, assumed, nw);
    } while (old != assumed);
#endif
}

__global__ void scatter_kernel(const int* __restrict__ ur, const int* __restrict__ uc,
                               const float* __restrict__ uv,
                               const int* __restrict__ gr, const int* __restrict__ gc,
                               const float* __restrict__ gv,
                               const int* __restrict__ dr, const int* __restrict__ dc,
                               const float* __restrict__ dv,
                               unsigned short* __restrict__ WUP,
                               unsigned short* __restrict__ WGATE,
                               unsigned short* __restrict__ WDOWN) {
    unsigned int i = blockIdx.x * blockDim.x + threadIdx.x;
    if (i < NNZ_) {
        add_bf16(WUP, ur[i] * DIM_ + uc[i], uv[i]);
    } else if (i < 2u * NNZ_) {
        unsigned int j = i - NNZ_;
        add_bf16(WGATE, gr[j] * DIM_ + gc[j], gv[j]);
    } else {
        unsigned int j = i - 2u * NNZ_;
        add_bf16(WDOWN, dr[j] * HIDDEN_ + dc[j], dv[j]);
    }
}

// ---------------------------------------------------------------- up+gate GEMM
// C[512][4096] tiles 64(M)x128(N), BK=32, 256 thr = 4 waves, wave-tile 32x64.
// Two K-passes (up then gate) reuse the block; epilogue: silu(u)*g -> HID bf16.
__global__ __launch_bounds__(256) void gemm_upgate_kernel(
    const unsigned short* __restrict__ xb,      // [512][1024]
    const unsigned short* __restrict__ wup,     // [4096][1024]
    const unsigned short* __restrict__ wgate,   // [4096][1024]
    const float* __restrict__ up_bias,
    const float* __restrict__ gate_bias,
    unsigned short* __restrict__ hid) {         // [512][4096]
    __shared__ unsigned short sA[64 * 32];
    __shared__ unsigned short sB[128 * 32];
    const int t = threadIdx.x;
    const int m0 = blockIdx.y * 64;
    const int n0 = blockIdx.x * 128;
    const int w = t >> 6, l = t & 63;
    const int wm = (w >> 1) * 32, wn = (w & 1) * 64;
    const int lr = l & 15, lkq = (l >> 4);

    float4v acc[2][2][4];
    for (int p = 0; p < 2; ++p)
        for (int im = 0; im < 2; ++im)
            for (int in = 0; in < 4; ++in)
                acc[p][im][in] = float4v{0.f, 0.f, 0.f, 0.f};

    const int srow = t >> 2, scol = (t & 3) * 8;

    for (int p = 0; p < 2; ++p) {
        const unsigned short* W = p ? wgate : wup;
        for (int k0 = 0; k0 < DIM_; k0 += 32) {
            async16(xb + (m0 + srow) * DIM_ + k0 + scol, &sA[t * 8]);
            async16(W + (n0 + srow) * DIM_ + k0 + scol, &sB[t * 8]);
            async16(W + (n0 + 64 + srow) * DIM_ + k0 + scol, &sB[(t + 256) * 8]);
            __syncthreads();
            short8 a[2], b[4];
            for (int im = 0; im < 2; ++im)
                a[im] = *(const short8*)&sA[(wm + im * 16 + lr) * 32 + lkq * 8];
            for (int in = 0; in < 4; ++in)
                b[in] = *(const short8*)&sB[(wn + in * 16 + lr) * 32 + lkq * 8];
            for (int im = 0; im < 2; ++im)
                for (int in = 0; in < 4; ++in)
                    acc[p][im][in] = __builtin_amdgcn_mfma_f32_16x16x32_bf16(
                        a[im], b[in], acc[p][im][in], 0, 0, 0);
            __syncthreads();
        }
    }

    for (int im = 0; im < 2; ++im) {
        for (int in = 0; in < 4; ++in) {
            const int n = n0 + wn + in * 16 + lr;
            const float ub = up_bias[n], gb = gate_bias[n];
            for (int r = 0; r < 4; ++r) {
                const int m = m0 + wm + im * 16 + lkq * 4 + r;
                const float u = acc[0][im][in][r] + ub;
                const float g = acc[1][im][in][r] + gb;
                const float h = (u / (1.f + __expf(-u))) * g;
                hid[m * HIDDEN_ + n] = f2bf(h);
            }
        }
    }
}

// ---------------------------------------------------------------- down GEMM
// C[512][1024] tiles 64x64, split-K=4, atomicAdd epilogue onto d_out
// (pre-initialized to x + down_bias by prep).
__global__ __launch_bounds__(256) void gemm_down_kernel(
    const unsigned short* __restrict__ hid,     // [512][4096]
    const unsigned short* __restrict__ wdown,   // [1024][4096]
    float* __restrict__ out) {                  // [512][1024]
    __shared__ unsigned short sA[64 * 32];
    __shared__ unsigned short sB[64 * 32];
    const int t = threadIdx.x;
    const int n0 = blockIdx.x * 64;
    const int m0 = blockIdx.y * 64;
    const int kb = blockIdx.z * 1024;
    const int w = t >> 6, l = t & 63;
    const int wm = (w >> 1) * 32, wn = (w & 1) * 32;
    const int lr = l & 15, lkq = (l >> 4);

    float4v acc[2][2];
    for (int im = 0; im < 2; ++im)
        for (int in = 0; in < 2; ++in)
            acc[im][in] = float4v{0.f, 0.f, 0.f, 0.f};

    const int srow = t >> 2, scol = (t & 3) * 8;

    for (int k0 = kb; k0 < kb + 1024; k0 += 32) {
        async16(hid + (m0 + srow) * HIDDEN_ + k0 + scol, &sA[t * 8]);
        async16(wdown + (n0 + srow) * HIDDEN_ + k0 + scol, &sB[t * 8]);
        __syncthreads();
        short8 a[2], b[2];
        for (int im = 0; im < 2; ++im)
            a[im] = *(const short8*)&sA[(wm + im * 16 + lr) * 32 + lkq * 8];
        for (int in = 0; in < 2; ++in)
            b[in] = *(const short8*)&sB[(wn + in * 16 + lr) * 32 + lkq * 8];
        for (int im = 0; im < 2; ++im)
            for (int in = 0; in < 2; ++in)
                acc[im][in] = __builtin_amdgcn_mfma_f32_16x16x32_bf16(
                    a[im], b[in], acc[im][in], 0, 0, 0);
        __syncthreads();
    }

    for (int im = 0; im < 2; ++im) {
        for (int in = 0; in < 2; ++in) {
            const int n = n0 + wn + in * 16 + lr;
            for (int r = 0; r < 4; ++r) {
                const int m = m0 + wm + im * 16 + lkq * 4 + r;
                atomicAdd(out + m * DIM_ + n, acc[im][in][r]);
            }
        }
    }
}

// ---------------------------------------------------------------- launch
extern "C" void kernel_launch(void* const* d_in, const int* in_sizes, int n_in,
                              void* d_out, int out_size, void* d_ws, size_t ws_size,
                              hipStream_t stream) {
    const float* x         = (const float*)d_in[0];
    const int*   up_row    = (const int*)d_in[1];
    const int*   up_col    = (const int*)d_in[2];
    const float* up_val    = (const float*)d_in[3];
    const float* up_bias   = (const float*)d_in[4];
    const int*   gate_row  = (const int*)d_in[5];
    const int*   gate_col  = (const int*)d_in[6];
    const float* gate_val  = (const float*)d_in[7];
    const float* gate_bias = (const float*)d_in[8];
    const int*   down_row  = (const int*)d_in[9];
    const int*   down_col  = (const int*)d_in[10];
    const float* down_val  = (const float*)d_in[11];
    const float* down_bias = (const float*)d_in[12];
    float* out = (float*)d_out;

    unsigned char* ws = (unsigned char*)d_ws;
    unsigned short* WUP   = (unsigned short*)(ws);
    unsigned short* WGATE = (unsigned short*)(ws + (8u << 20));
    unsigned short* WDOWN = (unsigned short*)(ws + (16u << 20));
    unsigned short* XB    = (unsigned short*)(ws + (24u << 20));
    unsigned short* HID   = (unsigned short*)(ws + (25u << 20));

    const unsigned int prep_total = ZN_ + 2 * XC_;   // 1,835,008 = 7168 * 256
    prep_kernel<<<prep_total / 256, 256, 0, stream>>>(
        x, down_bias, (uint4*)ws, XB, out);

    scatter_kernel<<<3 * NNZ_ / 256, 256, 0, stream>>>(
        up_row, up_col, up_val, gate_row, gate_col, gate_val,
        down_row, down_col, down_val, WUP, WGATE, WDOWN);

    gemm_upgate_kernel<<<dim3(HIDDEN_ / 128, TTOK_ / 64), 256, 0, stream>>>(
        XB, WUP, WGATE, up_bias, gate_bias, HID);

    gemm_down_kernel<<<dim3(DIM_ / 64, TTOK_ / 64, 4), 256, 0, stream>>>(
        HID, WDOWN, out);
}